// Round 15
// baseline (147.358 us; speedup 1.0000x reference)
//
#include <hip/hip_runtime.h>
#include <hip/hip_bf16.h>
#include <math.h>

#define XCOLS 921
#define COL_Z 0
#define COL_D 64
#define COL_INVD 184
#define COL_INVSQ 304
#define COL_EXPD 424
#define COL_SCR 544
#define COL_LOGD 664
#define COL_PW 784
#define COL_ND 904
#define COL_GL 920

#define BATCH 2048
#define NPAIRS 120
#define RPW (BATCH * NPAIRS)
#define RND (BATCH * 16)
#define RGL BATCH

#define ROWS_BLK 128
#define GL_BLK 16
#define PW_BLK 1920
#define ND_BLK 256

#define PRE_SG   512
#define PRE_WP   128

// ---- d_ws byte offsets ----
#define WS_SGATE   0u
#define WS_BW3_PW  8704u
#define WS_BW3_ND  12800u
#define WS_BW3_GL  16896u
#define WS_B1D_GL  20992u
#define WS_W1T_PW  23040u          /* [8][64][16] bf16: k<8 W1, k==8 b1 */
#define WS_W1T_ND  39424u
#define WS_W1T_GL  55808u          /* [8][64][64] bf16 */
#define WS_W2T_PW  121344u         /* [8][8kb][64col][8e] bf16 */
#define WS_W2T_ND  186880u
#define WS_W2T_GL  252416u

typedef unsigned short ushort_t;
typedef unsigned int uint_t;
typedef __attribute__((ext_vector_type(8))) short bf16x8;
typedef __attribute__((ext_vector_type(4))) float f32x4;

__device__ __forceinline__ float fast_rcp(float x) { return __builtin_amdgcn_rcpf(x); }
__device__ __forceinline__ float silu_f(float x) { return x * fast_rcp(1.0f + __expf(-x)); }
__device__ __forceinline__ ushort_t f2b(float f) {
    __hip_bfloat16 h = __float2bfloat16(f);
    return __builtin_bit_cast(ushort_t, h);
}
__device__ __forceinline__ uint_t pk2(float a, float b) {
    return (uint_t)f2b(a) | ((uint_t)f2b(b) << 16);
}
__device__ __forceinline__ int permS(int m) {
    return ((m >> 2) & 3) * 8 + (m & 3) + ((m >> 4) & 1) * 4 + ((m >> 5) & 1) * 32;
}

struct AArgs { const float *aW1, *ab1, *aW2, *ab2, *b3, *scale, *res; };
struct PArgs { const float *W1, *b1, *W2, *b2, *W3; };
struct SArgs { const float *W1, *b1, *W2, *b2, *W3, *b3; };

// ================= pre: selgeom | weight-prep =================
__global__ __launch_bounds__(256) void pre_kernel(
    const float* __restrict__ z,
    SArgs sel,
    PArgs ppw, PArgs pnd, PArgs pgl,
    char* __restrict__ ws, float* __restrict__ out)
{
    const int bid = blockIdx.x;
    const int tid = threadIdx.x;

    if (bid < PRE_SG) {
        __shared__ float zs[4][64];
        __shared__ float h1[4][64];
        __shared__ float h2s[4][32];
        __shared__ float sgv[4];
        const int grp = tid >> 6, tl = tid & 63;
        const int b = bid * 4 + grp;
        zs[grp][tl] = z[b * 64 + tl];
        __syncthreads();
        {
            float acc = sel.b1[tl];
            #pragma unroll
            for (int i = 0; i < 64; ++i) acc += zs[grp][i] * sel.W1[i * 64 + tl];
            h1[grp][tl] = silu_f(acc);
        }
        __syncthreads();
        if (tl < 32) {
            float acc = sel.b2[tl];
            #pragma unroll
            for (int i = 0; i < 64; ++i) acc += h1[grp][i] * sel.W2[i * 32 + tl];
            h2s[grp][tl] = silu_f(acc);
        }
        __syncthreads();
        if (tl == 0) {
            float acc = sel.b3[0];
            #pragma unroll
            for (int i = 0; i < 32; ++i) acc += h2s[grp][i] * sel.W3[i];
            float s = fast_rcp(1.0f + __expf(-acc));
            sgv[grp] = s;
            ((float*)(ws + WS_SGATE))[b] = s;
        }
        __syncthreads();
        float s = sgv[grp];
        float* row = out + (size_t)b * XCOLS;
        {
            float v = zs[grp][tl] * s;
            row[COL_Z + tl] = fminf(fmaxf(v, -1e6f), 1e6f);
        }
        #pragma unroll
        for (int rep = 0; rep < 2; ++rep) {
            int p = tl + rep * 64;
            if (p < NPAIRS) {
                int i = 0, pp = p;
                while (pp >= 15 - i) { pp -= 15 - i; ++i; }
                int j = i + 1 + pp;
                float dx = zs[grp][i * 4 + 0] - zs[grp][j * 4 + 0];
                float dy = zs[grp][i * 4 + 1] - zs[grp][j * 4 + 1];
                float d = sqrtf(dx * dx + dy * dy);
                d = fmaxf(d, 0.001f);
                float inv_d = fast_rcp(d + 0.1f);
                float inv_sq = fast_rcp(d * d + 0.1f);
                float exp_d = __expf(-fminf(d, 20.0f));
                float screened = exp_d * inv_d;
                float log_d = __logf(d + 1.0f);
                row[COL_D + p] = d * s;
                row[COL_INVD + p] = inv_d * s;
                row[COL_INVSQ + p] = inv_sq * s;
                row[COL_EXPD + p] = exp_d * s;
                row[COL_SCR + p] = screened * s;
                row[COL_LOGD + p] = log_d * s;
            }
        }
        return;
    }

    // ---------- weight prep (grid-stride over 128 blocks) ----------
    int t0 = (bid - PRE_SG) * 256 + tid;
    const int STR = PRE_WP * 256;
    for (int t = t0; t < 16384; t += STR) {
        int which = t >> 13, u = t & 8191;
        int nn = u >> 10, m = (u >> 4) & 63, k = u & 15;
        int sm = permS(m);
        float v;
        if (which == 0)
            v = (k < 8) ? ppw.W1[nn * 512 + k * 64 + sm]
              : (k == 8 ? ppw.b1[nn * 64 + sm] : 0.f);
        else
            v = (k < 4) ? pnd.W1[nn * 256 + k * 64 + sm]
              : (k == 8 ? pnd.b1[nn * 64 + sm] : 0.f);
        ((ushort_t*)(ws + (which == 0 ? WS_W1T_PW : WS_W1T_ND)))[u] = f2b(v);
    }
    for (int t = t0; t < 32768; t += STR) {
        int nn = t >> 12, m = (t >> 6) & 63, k = t & 63;
        ((ushort_t*)(ws + WS_W1T_GL))[t] = f2b(pgl.W1[nn * 4096 + k * 64 + permS(m)]);
    }
    for (int t = t0; t < 512; t += STR) {
        int nn = t >> 6, m = t & 63;
        ((float*)(ws + WS_B1D_GL))[t] = pgl.b1[nn * 64 + permS(m)];
    }
    for (int t = t0; t < 3 * 32768; t += STR) {
        int which = t >> 15, u = t & 32767;
        int nn = u >> 12, kb = (u >> 9) & 7, col = (u >> 3) & 63, e = u & 7;
        int k = (kb & 3) * 8 + e + ((kb >> 2) << 5);
        const float* src = which == 0 ? ppw.W2 : which == 1 ? pnd.W2 : pgl.W2;
        ushort_t* dst = (ushort_t*)(ws + (which == 0 ? WS_W2T_PW : which == 1 ? WS_W2T_ND : WS_W2T_GL));
        dst[u] = f2b(src[nn * 4096 + k * 64 + col]);
    }
    for (int t = t0; t < 1536; t += STR) {
        int which = t >> 9, u = t & 511;
        const float* b2 = which == 0 ? ppw.b2 : which == 1 ? pnd.b2 : pgl.b2;
        const float* W3 = which == 0 ? ppw.W3 : which == 1 ? pnd.W3 : pgl.W3;
        float2* dst = (float2*)(ws + (which == 0 ? WS_BW3_PW : which == 1 ? WS_BW3_ND : WS_BW3_GL));
        dst[u] = make_float2(b2[u], W3[u]);
    }
}

// ================= fused basis kernel: phase A 2-way split; basis loop w/ LDS-dbuf W2 =================
// grid: gl [0,16) | pw [16,1936) | nd [1936,2192); 512 thr = 8 waves; wave w owns rows w*16..w*16+15
__global__ __launch_bounds__(512, 4) void basis_main_kernel(
    const char* __restrict__ ws, const float* __restrict__ z,
    AArgs apw, AArgs anda, AArgs agl,
    float* __restrict__ out)
{
    __shared__ __align__(16) ushort_t W2L[2][4096];   // 16 KB dbuf; W2L[1] doubles as phase-A scratch
    __shared__ float Att[ROWS_BLK * 9];               // [row][0..7]=att*scale, [8]=tail
    __shared__ __align__(16) uint_t XfS[ROWS_BLK][36];

    const int tid = threadIdx.x;
    const int lane = tid & 63;
    const int wave = tid >> 6;
    const int g = lane >> 4;
    const int lo = lane & 15;

    const int bid = blockIdx.x;
    int fam, rowbase;
    uint_t w1t_off, w2t_off, bw3_off;
    if (bid < GL_BLK) {
        fam = 2; rowbase = bid * ROWS_BLK;
        w1t_off = WS_W1T_GL; w2t_off = WS_W2T_GL; bw3_off = WS_BW3_GL;
    } else if (bid < GL_BLK + PW_BLK) {
        fam = 0; rowbase = (bid - GL_BLK) * ROWS_BLK;
        w1t_off = WS_W1T_PW; w2t_off = WS_W2T_PW; bw3_off = WS_BW3_PW;
    } else {
        fam = 1; rowbase = (bid - (GL_BLK + PW_BLK)) * ROWS_BLK;
        w1t_off = WS_W1T_ND; w2t_off = WS_W2T_ND; bw3_off = WS_BW3_ND;
    }
    const AArgs A = (fam == 0) ? apw : (fam == 1) ? anda : agl;

    // prologue: load basis-0 W2 chunk (16 B/thread) into regs
    uint4 stg = *(const uint4*)(ws + w2t_off + (uint_t)tid * 16u);

    float* scr = (float*)&W2L[1][0];   // 4.6 KB phase-A scratch (free until loop n=0 bottom)

    // ---- Phase A (tid<256): 2 threads/row, 16 attention units each ----
    float lgv[8];
    float mean = 0.f;
    if (tid < 2 * ROWS_BLK) {
        const int r = tid & (ROWS_BLK - 1);
        const int ug = tid >> 7;              // 0 or 1
        const int rg = rowbase + r;
        #pragma unroll
        for (int nn = 0; nn < 8; ++nn) lgv[nn] = (ug == 0) ? A.ab2[nn] : 0.f;
        if (fam == 0) {
            int b = rg / 120, p = rg - b * 120;
            int i = 0, pp = p;
            while (pp >= 15 - i) { pp -= 15 - i; ++i; }
            int j = i + 1 + pp;
            const float* zb = z + b * 64;
            float4 xa = *(const float4*)(zb + i * 4);
            float4 xb = *(const float4*)(zb + j * 4);
            float x[8] = {xa.x, xa.y, xa.z, xa.w, xb.x, xb.y, xb.z, xb.w};
            if (ug == 0) {
                *(uint4*)&XfS[r][0] = make_uint4(pk2(x[0], x[1]), pk2(x[2], x[3]),
                                                 pk2(x[4], x[5]), pk2(x[6], x[7]));
                mean = (x[0]+x[1]+x[2]+x[3]+x[4]+x[5]+x[6]+x[7]) * 0.125f;
            }
            #pragma unroll
            for (int u = 0; u < 16; ++u) {
                int unit = ug * 16 + u;
                float acc = A.ab1[unit];
                #pragma unroll
                for (int q = 0; q < 8; ++q) acc += x[q] * A.aW1[q * 32 + unit];
                float a1 = silu_f(acc);
                #pragma unroll
                for (int nn = 0; nn < 8; ++nn) lgv[nn] += a1 * A.aW2[unit * 8 + nn];
            }
        } else if (fam == 1) {
            int b = rg >> 4, node = rg & 15;
            float4 xa = *(const float4*)(z + b * 64 + node * 4);
            float x[4] = {xa.x, xa.y, xa.z, xa.w};
            if (ug == 0) {
                *(uint4*)&XfS[r][0] = make_uint4(pk2(x[0], x[1]), pk2(x[2], x[3]), 0u, 0u);
                mean = (x[0]+x[1]+x[2]+x[3]) * 0.25f;
            }
            #pragma unroll
            for (int u = 0; u < 16; ++u) {
                int unit = ug * 16 + u;
                float acc = A.ab1[unit];
                #pragma unroll
                for (int q = 0; q < 4; ++q) acc += x[q] * A.aW1[q * 32 + unit];
                float a1 = silu_f(acc);
                #pragma unroll
                for (int nn = 0; nn < 8; ++nn) lgv[nn] += a1 * A.aW2[unit * 8 + nn];
            }
        } else {
            const float* zr = z + (size_t)rg * 64;
            float a1acc[16];
            #pragma unroll
            for (int u = 0; u < 16; ++u) a1acc[u] = A.ab1[ug * 16 + u];
            float mn = 0.f;
            #pragma unroll
            for (int c = 0; c < 8; ++c) {
                float4 f0 = *(const float4*)(zr + c * 8);
                float4 f1 = *(const float4*)(zr + c * 8 + 4);
                float xs[8] = {f0.x, f0.y, f0.z, f0.w, f1.x, f1.y, f1.z, f1.w};
                if (ug == 0) {
                    *(uint4*)&XfS[r][c * 4] = make_uint4(pk2(xs[0], xs[1]), pk2(xs[2], xs[3]),
                                                         pk2(xs[4], xs[5]), pk2(xs[6], xs[7]));
                }
                #pragma unroll
                for (int q = 0; q < 8; ++q) {
                    mn += xs[q];
                    float xk = xs[q];
                    #pragma unroll
                    for (int u = 0; u < 16; ++u)
                        a1acc[u] += xk * A.aW1[(c * 8 + q) * 32 + ug * 16 + u];
                }
            }
            if (ug == 0) mean = mn * (1.0f / 64.0f);
            #pragma unroll
            for (int u = 0; u < 16; ++u) {
                float a1 = silu_f(a1acc[u]);
                #pragma unroll
                for (int nn = 0; nn < 8; ++nn) lgv[nn] += a1 * A.aW2[(ug * 16 + u) * 8 + nn];
            }
        }
        if (tid >= ROWS_BLK) {   // ug==1 -> scratch
            #pragma unroll
            for (int nn = 0; nn < 8; ++nn) scr[r * 9 + nn] = lgv[nn];
        }
    }
    __syncthreads();   // B1: scratch ready

    // combine + softmax (tid<128; own lgv + partner's scratch)
    if (tid < ROWS_BLK) {
        float lg[8];
        #pragma unroll
        for (int nn = 0; nn < 8; ++nn) lg[nn] = lgv[nn] + scr[tid * 9 + nn];
        float m = lg[0];
        #pragma unroll
        for (int nn = 1; nn < 8; ++nn) m = fmaxf(m, lg[nn]);
        float sum = 0.f;
        #pragma unroll
        for (int nn = 0; nn < 8; ++nn) { lg[nn] = __expf(lg[nn] - m); sum += lg[nn]; }
        float inv = fast_rcp(sum);
        float tail = 0.f;
        #pragma unroll
        for (int nn = 0; nn < 8; ++nn) {
            float a_n = lg[nn] * inv * A.scale[nn];
            tail += a_n * A.b3[nn];
            Att[tid * 9 + nn] = a_n;
        }
        Att[tid * 9 + 8] = tail + A.res[0] * mean;
    }
    // write basis-0 stage into W2L[0] (disjoint from scratch region)
    *(uint4*)((char*)&W2L[0][0] + (uint_t)tid * 16u) = stg;
    __syncthreads();   // B2: Att + W2L[0] ready; scratch dead

    // constant x-fragment (fam 0/1, g==1: k8 slot = 1.0 for bias row)
    union { bf16x8 v; ushort_t u[8]; } xc;
    #pragma unroll
    for (int e = 0; e < 8; ++e) xc.u[e] = 0;
    if (g == 1) xc.u[0] = f2b(1.0f);
    const bf16x8 zfr = {0, 0, 0, 0, 0, 0, 0, 0};

    const int rowl0 = wave * 16 + g * 4;
    float S0 = 0.f, S1 = 0.f, S2 = 0.f, S3 = 0.f;

    #pragma unroll 1
    for (int n = 0; n < 8; ++n) {
        uint4 nstg;
        if (n < 7) nstg = *(const uint4*)(ws + w2t_off + (uint_t)(n + 1) * 8192u + (uint_t)tid * 16u);
        const char* wbuf = (const char*)&W2L[n & 1][0];

        union { bf16x8 v; uint_t u[4]; } A0, A1;
        if (fam != 2) {
            bf16x8 af0 = zfr, af1 = zfr, af2 = zfr, af3 = zfr;
            if (g < 2) {
                const char* ab = ws + w1t_off + (uint_t)(n * 2048 + lo * 32 + g * 16);
                af0 = *(const bf16x8*)(ab + 0 * 512);
                af1 = *(const bf16x8*)(ab + 1 * 512);
                af2 = *(const bf16x8*)(ab + 2 * 512);
                af3 = *(const bf16x8*)(ab + 3 * 512);
            }
            bf16x8 xf = (g == 0) ? *(const bf16x8*)&XfS[wave * 16 + lo][0] : xc.v;
            const f32x4 zr4 = {0.f, 0.f, 0.f, 0.f};
            f32x4 d0 = __builtin_amdgcn_mfma_f32_16x16x32_bf16(af0, xf, zr4, 0, 0, 0);
            f32x4 d1 = __builtin_amdgcn_mfma_f32_16x16x32_bf16(af1, xf, zr4, 0, 0, 0);
            f32x4 d2 = __builtin_amdgcn_mfma_f32_16x16x32_bf16(af2, xf, zr4, 0, 0, 0);
            f32x4 d3 = __builtin_amdgcn_mfma_f32_16x16x32_bf16(af3, xf, zr4, 0, 0, 0);
            A0.u[0] = pk2(silu_f(d0[0]), silu_f(d0[1]));
            A0.u[1] = pk2(silu_f(d0[2]), silu_f(d0[3]));
            A0.u[2] = pk2(silu_f(d1[0]), silu_f(d1[1]));
            A0.u[3] = pk2(silu_f(d1[2]), silu_f(d1[3]));
            A1.u[0] = pk2(silu_f(d2[0]), silu_f(d2[1]));
            A1.u[1] = pk2(silu_f(d2[2]), silu_f(d2[3]));
            A1.u[2] = pk2(silu_f(d3[0]), silu_f(d3[1]));
            A1.u[3] = pk2(silu_f(d3[2]), silu_f(d3[3]));
        } else {
            float4 b1r0 = *(const float4*)(ws + WS_B1D_GL + (uint_t)(n * 64 + 0 * 16 + g * 4) * 4u);
            float4 b1r1 = *(const float4*)(ws + WS_B1D_GL + (uint_t)(n * 64 + 1 * 16 + g * 4) * 4u);
            float4 b1r2 = *(const float4*)(ws + WS_B1D_GL + (uint_t)(n * 64 + 2 * 16 + g * 4) * 4u);
            float4 b1r3 = *(const float4*)(ws + WS_B1D_GL + (uint_t)(n * 64 + 3 * 16 + g * 4) * 4u);
            const char* w1b = ws + w1t_off + (uint_t)(n * 8192 + g * 16 + lo * 128);
            const int row = wave * 16 + lo;
            bf16x8 xf0 = *(const bf16x8*)&XfS[row][g * 4];
            bf16x8 xf1 = *(const bf16x8*)&XfS[row][16 + g * 4];
            const f32x4 zr4 = {0.f, 0.f, 0.f, 0.f};
            f32x4 d0 = __builtin_amdgcn_mfma_f32_16x16x32_bf16(*(const bf16x8*)(w1b + 0), xf0, zr4, 0, 0, 0);
            d0 = __builtin_amdgcn_mfma_f32_16x16x32_bf16(*(const bf16x8*)(w1b + 64), xf1, d0, 0, 0, 0);
            f32x4 d1 = __builtin_amdgcn_mfma_f32_16x16x32_bf16(*(const bf16x8*)(w1b + 2048), xf0, zr4, 0, 0, 0);
            d1 = __builtin_amdgcn_mfma_f32_16x16x32_bf16(*(const bf16x8*)(w1b + 2112), xf1, d1, 0, 0, 0);
            f32x4 d2 = __builtin_amdgcn_mfma_f32_16x16x32_bf16(*(const bf16x8*)(w1b + 4096), xf0, zr4, 0, 0, 0);
            d2 = __builtin_amdgcn_mfma_f32_16x16x32_bf16(*(const bf16x8*)(w1b + 4160), xf1, d2, 0, 0, 0);
            f32x4 d3 = __builtin_amdgcn_mfma_f32_16x16x32_bf16(*(const bf16x8*)(w1b + 6144), xf0, zr4, 0, 0, 0);
            d3 = __builtin_amdgcn_mfma_f32_16x16x32_bf16(*(const bf16x8*)(w1b + 6208), xf1, d3, 0, 0, 0);
            A0.u[0] = pk2(silu_f(d0[0] + b1r0.x), silu_f(d0[1] + b1r0.y));
            A0.u[1] = pk2(silu_f(d0[2] + b1r0.z), silu_f(d0[3] + b1r0.w));
            A0.u[2] = pk2(silu_f(d1[0] + b1r1.x), silu_f(d1[1] + b1r1.y));
            A0.u[3] = pk2(silu_f(d1[2] + b1r1.z), silu_f(d1[3] + b1r1.w));
            A1.u[0] = pk2(silu_f(d2[0] + b1r2.x), silu_f(d2[1] + b1r2.y));
            A1.u[1] = pk2(silu_f(d2[2] + b1r2.z), silu_f(d2[3] + b1r2.w));
            A1.u[2] = pk2(silu_f(d3[0] + b1r3.x), silu_f(d3[1] + b1r3.y));
            A1.u[3] = pk2(silu_f(d3[2] + b1r3.z), silu_f(d3[3] + b1r3.w));
        }

        float pv0 = 0.f, pv1 = 0.f, pv2 = 0.f, pv3 = 0.f;
        #pragma unroll
        for (int cb = 0; cb < 4; ++cb) {
            bf16x8 bf0 = *(const bf16x8*)(wbuf + (uint_t)((g * 64 + cb * 16 + lo) * 16));
            bf16x8 bf1 = *(const bf16x8*)(wbuf + (uint_t)(((g + 4) * 64 + cb * 16 + lo) * 16));
            float2 bwv = *(const float2*)(ws + bw3_off + (uint_t)(n * 64 + cb * 16 + lo) * 8u);
            f32x4 cinit = {bwv.x, bwv.x, bwv.x, bwv.x};
            f32x4 acc = __builtin_amdgcn_mfma_f32_16x16x32_bf16(A0.v, bf0, cinit, 0, 0, 0);
            acc = __builtin_amdgcn_mfma_f32_16x16x32_bf16(A1.v, bf1, acc, 0, 0, 0);
            pv0 += silu_f(acc[0]) * bwv.y;
            pv1 += silu_f(acc[1]) * bwv.y;
            pv2 += silu_f(acc[2]) * bwv.y;
            pv3 += silu_f(acc[3]) * bwv.y;
        }
        S0 += Att[(rowl0 + 0) * 9 + n] * pv0;
        S1 += Att[(rowl0 + 1) * 9 + n] * pv1;
        S2 += Att[(rowl0 + 2) * 9 + n] * pv2;
        S3 += Att[(rowl0 + 3) * 9 + n] * pv3;

        if (n < 7) *(uint4*)((char*)&W2L[(n + 1) & 1][0] + (uint_t)tid * 16u) = nstg;
        __syncthreads();
    }

    // ---- final: one 16-lane reduce, gate, clip, store ----
    float Sv[4] = {S0, S1, S2, S3};
    #pragma unroll
    for (int r = 0; r < 4; ++r) {
        float v = Sv[r];
        v += __shfl_xor(v, 1);
        v += __shfl_xor(v, 2);
        v += __shfl_xor(v, 4);
        v += __shfl_xor(v, 8);
        if (lo == 0) {
            int row = rowl0 + r;
            int rg = rowbase + row;
            int bb, colo;
            if (fam == 0) { bb = rg / 120; colo = COL_PW + (rg - bb * 120); }
            else if (fam == 1) { bb = rg >> 4; colo = COL_ND + (rg & 15); }
            else { bb = rg; colo = COL_GL; }
            float o = (v + Att[row * 9 + 8]) * ((const float*)(ws + WS_SGATE))[bb];
            o = fminf(fmaxf(o, -1e6f), 1e6f);
            out[(size_t)bb * XCOLS + colo] = o;
        }
    }
}

extern "C" void kernel_launch(void* const* d_in, const int* in_sizes, int n_in,
                              void* d_out, int out_size, void* d_ws, size_t ws_size,
                              hipStream_t stream) {
    const float* z = (const float*)d_in[0];
    const float* pw[12]; const float* nd[12]; const float* gl[12];
    for (int i = 0; i < 12; ++i) pw[i] = (const float*)d_in[1 + i];
    for (int i = 0; i < 12; ++i) nd[i] = (const float*)d_in[13 + i];
    for (int i = 0; i < 12; ++i) gl[i] = (const float*)d_in[25 + i];

    SArgs sel = {(const float*)d_in[37], (const float*)d_in[38], (const float*)d_in[39],
                 (const float*)d_in[40], (const float*)d_in[41], (const float*)d_in[42]};

    float* out = (float*)d_out;
    char* ws = (char*)d_ws;

    AArgs apw = {pw[7], pw[8], pw[9], pw[10], pw[5], pw[6], pw[11]};
    AArgs anda = {nd[7], nd[8], nd[9], nd[10], nd[5], nd[6], nd[11]};
    AArgs agl = {gl[7], gl[8], gl[9], gl[10], gl[5], gl[6], gl[11]};
    PArgs ppw = {pw[0], pw[1], pw[2], pw[3], pw[4]};
    PArgs pnd = {nd[0], nd[1], nd[2], nd[3], nd[4]};
    PArgs pgl = {gl[0], gl[1], gl[2], gl[3], gl[4]};

    pre_kernel<<<PRE_SG + PRE_WP, 256, 0, stream>>>(z, sel, ppw, pnd, pgl, ws, out);

    basis_main_kernel<<<GL_BLK + PW_BLK + ND_BLK, 512, 0, stream>>>(
        ws, z, apw, anda, agl, out);
}

// Round 16
// 127.242 us; speedup vs baseline: 1.1581x; 1.1581x over previous
//
#include <hip/hip_runtime.h>
#include <hip/hip_bf16.h>
#include <math.h>

#define XCOLS 921
#define COL_Z 0
#define COL_D 64
#define COL_INVD 184
#define COL_INVSQ 304
#define COL_EXPD 424
#define COL_SCR 544
#define COL_LOGD 664
#define COL_PW 784
#define COL_ND 904
#define COL_GL 920

#define BATCH 2048
#define NPAIRS 120
#define RPW (BATCH * NPAIRS)       /* 245760 */
#define RND (BATCH * 16)           /* 32768  */
#define RGL BATCH                  /* 2048   */

#define ROWS_BLK 128
#define TILES 8
#define GL_BLK 16                  /* 2048/128  */
#define PW_BLK 1920                /* 245760/128 */
#define ND_BLK 256                 /* 32768/128 */

/* pre grid: [0,512) selgeom(4 rows/blk) | [512,640) weight-prep */
#define PRE_SG   512
#define PRE_WP   128

// ---- d_ws byte offsets (weights + gate only) ----
#define WS_SGATE   0u
#define WS_BW3_PW  8704u
#define WS_BW3_ND  12800u
#define WS_BW3_GL  16896u
#define WS_B1D_GL  20992u
#define WS_W1T_PW  23040u          /* [8][64][16] bf16: k<8 W1, k==8 b1 */
#define WS_W1T_ND  39424u
#define WS_W1T_GL  55808u          /* [8][64][64] bf16 */
#define WS_W2T_PW  121344u         /* [8][8kb][64col][8e] bf16 */
#define WS_W2T_ND  186880u
#define WS_W2T_GL  252416u

typedef unsigned short ushort_t;
typedef unsigned int uint_t;
typedef __attribute__((ext_vector_type(8))) short bf16x8;
typedef __attribute__((ext_vector_type(4))) float f32x4;

__device__ __forceinline__ float fast_rcp(float x) { return __builtin_amdgcn_rcpf(x); }
__device__ __forceinline__ float silu_f(float x) { return x * fast_rcp(1.0f + __expf(-x)); }
__device__ __forceinline__ ushort_t f2b(float f) {
    __hip_bfloat16 h = __float2bfloat16(f);
    return __builtin_bit_cast(ushort_t, h);
}
__device__ __forceinline__ uint_t pk2(float a, float b) {
    return (uint_t)f2b(a) | ((uint_t)f2b(b) << 16);
}
// h1-unit permutation: MFMA-row m holds original unit permS(m)
__device__ __forceinline__ int permS(int m) {
    return ((m >> 2) & 3) * 8 + (m & 3) + ((m >> 4) & 1) * 4 + ((m >> 5) & 1) * 32;
}

struct AArgs { const float *aW1, *ab1, *aW2, *ab2, *b3, *scale, *res; };
struct PArgs { const float *W1, *b1, *W2, *b2, *W3; };
struct SArgs { const float *W1, *b1, *W2, *b2, *W3, *b3; };

// ================= pre: selgeom | weight-prep =================
__global__ __launch_bounds__(256) void pre_kernel(
    const float* __restrict__ z,
    SArgs sel,
    PArgs ppw, PArgs pnd, PArgs pgl,
    char* __restrict__ ws, float* __restrict__ out)
{
    const int bid = blockIdx.x;
    const int tid = threadIdx.x;

    if (bid < PRE_SG) {
        __shared__ float zs[4][64];
        __shared__ float h1[4][64];
        __shared__ float h2s[4][32];
        __shared__ float sgv[4];
        const int grp = tid >> 6, tl = tid & 63;
        const int b = bid * 4 + grp;
        zs[grp][tl] = z[b * 64 + tl];
        __syncthreads();
        {
            float acc = sel.b1[tl];
            #pragma unroll
            for (int i = 0; i < 64; ++i) acc += zs[grp][i] * sel.W1[i * 64 + tl];
            h1[grp][tl] = silu_f(acc);
        }
        __syncthreads();
        if (tl < 32) {
            float acc = sel.b2[tl];
            #pragma unroll
            for (int i = 0; i < 64; ++i) acc += h1[grp][i] * sel.W2[i * 32 + tl];
            h2s[grp][tl] = silu_f(acc);
        }
        __syncthreads();
        if (tl == 0) {
            float acc = sel.b3[0];
            #pragma unroll
            for (int i = 0; i < 32; ++i) acc += h2s[grp][i] * sel.W3[i];
            float s = fast_rcp(1.0f + __expf(-acc));
            sgv[grp] = s;
            ((float*)(ws + WS_SGATE))[b] = s;
        }
        __syncthreads();
        float s = sgv[grp];
        float* row = out + (size_t)b * XCOLS;
        {
            float v = zs[grp][tl] * s;
            row[COL_Z + tl] = fminf(fmaxf(v, -1e6f), 1e6f);
        }
        #pragma unroll
        for (int rep = 0; rep < 2; ++rep) {
            int p = tl + rep * 64;
            if (p < NPAIRS) {
                int i = 0, pp = p;
                while (pp >= 15 - i) { pp -= 15 - i; ++i; }
                int j = i + 1 + pp;
                float dx = zs[grp][i * 4 + 0] - zs[grp][j * 4 + 0];
                float dy = zs[grp][i * 4 + 1] - zs[grp][j * 4 + 1];
                float d = sqrtf(dx * dx + dy * dy);
                d = fmaxf(d, 0.001f);
                float inv_d = fast_rcp(d + 0.1f);
                float inv_sq = fast_rcp(d * d + 0.1f);
                float exp_d = __expf(-fminf(d, 20.0f));
                float screened = exp_d * inv_d;
                float log_d = __logf(d + 1.0f);
                row[COL_D + p] = d * s;
                row[COL_INVD + p] = inv_d * s;
                row[COL_INVSQ + p] = inv_sq * s;
                row[COL_EXPD + p] = exp_d * s;
                row[COL_SCR + p] = screened * s;
                row[COL_LOGD + p] = log_d * s;
            }
        }
        return;
    }

    // ---------- weight prep (grid-stride over 128 blocks) ----------
    int t0 = (bid - PRE_SG) * 256 + tid;
    const int STR = PRE_WP * 256;
    for (int t = t0; t < 16384; t += STR) {
        int which = t >> 13, u = t & 8191;
        int nn = u >> 10, m = (u >> 4) & 63, k = u & 15;
        int sm = permS(m);
        float v;
        if (which == 0)
            v = (k < 8) ? ppw.W1[nn * 512 + k * 64 + sm]
              : (k == 8 ? ppw.b1[nn * 64 + sm] : 0.f);
        else
            v = (k < 4) ? pnd.W1[nn * 256 + k * 64 + sm]
              : (k == 8 ? pnd.b1[nn * 64 + sm] : 0.f);
        ((ushort_t*)(ws + (which == 0 ? WS_W1T_PW : WS_W1T_ND)))[u] = f2b(v);
    }
    for (int t = t0; t < 32768; t += STR) {
        int nn = t >> 12, m = (t >> 6) & 63, k = t & 63;
        ((ushort_t*)(ws + WS_W1T_GL))[t] = f2b(pgl.W1[nn * 4096 + k * 64 + permS(m)]);
    }
    for (int t = t0; t < 512; t += STR) {
        int nn = t >> 6, m = t & 63;
        ((float*)(ws + WS_B1D_GL))[t] = pgl.b1[nn * 64 + permS(m)];
    }
    for (int t = t0; t < 3 * 32768; t += STR) {
        int which = t >> 15, u = t & 32767;
        int nn = u >> 12, kb = (u >> 9) & 7, col = (u >> 3) & 63, e = u & 7;
        int k = (kb & 3) * 8 + e + ((kb >> 2) << 5);
        const float* src = which == 0 ? ppw.W2 : which == 1 ? pnd.W2 : pgl.W2;
        ushort_t* dst = (ushort_t*)(ws + (which == 0 ? WS_W2T_PW : which == 1 ? WS_W2T_ND : WS_W2T_GL));
        dst[u] = f2b(src[nn * 4096 + k * 64 + col]);
    }
    for (int t = t0; t < 1536; t += STR) {
        int which = t >> 9, u = t & 511;
        const float* b2 = which == 0 ? ppw.b2 : which == 1 ? pnd.b2 : pgl.b2;
        const float* W3 = which == 0 ? ppw.W3 : which == 1 ? pnd.W3 : pgl.W3;
        float2* dst = (float2*)(ws + (which == 0 ? WS_BW3_PW : which == 1 ? WS_BW3_ND : WS_BW3_GL));
        dst[u] = make_float2(b2[u], W3[u]);
    }
}

// ================= fused basis kernel: phase A (attention+x-pack in LDS) + phase B (R8 loop) =================
// grid: gl [0,16) | pw [16,1936) | nd [1936,2192); 512 thr = 8 waves = 8 bases
__global__ __launch_bounds__(512, 4) void basis_main_kernel(
    const char* __restrict__ ws, const float* __restrict__ z,
    AArgs apw, AArgs anda, AArgs agl,
    float* __restrict__ out)
{
    __shared__ float Att[ROWS_BLK * 9];     // [row][0..7]=att*scale, [8]=tail
    __shared__ float Part[8][ROWS_BLK];
    __shared__ float lgp[4][ROWS_BLK][9];   // attention partials (pad 9)
    __shared__ float meanL[ROWS_BLK];
    __shared__ uint_t XfS[ROWS_BLK][36];    // x bf16 rows: pw/nd 4 dwords, gl 32 dwords (pad->36)

    const int tid = threadIdx.x;
    const int lane = tid & 63;
    const int n = tid >> 6;               // wave index == basis index
    const int g = lane >> 4;
    const int lo = lane & 15;

    const int bid = blockIdx.x;
    int fam, rowbase;
    uint_t w1t_off, w2t_off, bw3_off;
    if (bid < GL_BLK) {
        fam = 2; rowbase = bid * ROWS_BLK;
        w1t_off = WS_W1T_GL; w2t_off = WS_W2T_GL; bw3_off = WS_BW3_GL;
    } else if (bid < GL_BLK + PW_BLK) {
        fam = 0; rowbase = (bid - GL_BLK) * ROWS_BLK;
        w1t_off = WS_W1T_PW; w2t_off = WS_W2T_PW; bw3_off = WS_BW3_PW;
    } else {
        fam = 1; rowbase = (bid - (GL_BLK + PW_BLK)) * ROWS_BLK;
        w1t_off = WS_W1T_ND; w2t_off = WS_W2T_ND; bw3_off = WS_BW3_ND;
    }
    const AArgs A = (fam == 0) ? apw : (fam == 1) ? anda : agl;

    // per-output-row store metadata + gate
    int st_bb = 0, st_colo = 0;
    float st_s = 0.f;
    if (tid < ROWS_BLK) {
        int rg = rowbase + tid;
        if (fam == 0) { st_bb = rg / 120; st_colo = COL_PW + (rg - st_bb * 120); }
        else if (fam == 1) { st_bb = rg >> 4; st_colo = COL_ND + (rg & 15); }
        else { st_bb = rg; st_colo = COL_GL; }
        st_s = ((const float*)(ws + WS_SGATE))[st_bb];
    }

    // ---- Phase A: per-row attention partials + x packing (low register footprint) ----
    {
        const int r = tid & (ROWS_BLK - 1);
        const int ug = tid >> 7;              // 0..3, units ug*8 .. ug*8+7
        const int rg = rowbase + r;
        float acc8[8];
        if (fam != 2) {
            float x[8];
            if (fam == 0) {
                int b = rg / 120, p = rg - b * 120;
                int i = 0, pp = p;
                while (pp >= 15 - i) { pp -= 15 - i; ++i; }
                int j = i + 1 + pp;
                const float* zb = z + b * 64;
                float4 xa = *(const float4*)(zb + i * 4);
                float4 xb = *(const float4*)(zb + j * 4);
                x[0] = xa.x; x[1] = xa.y; x[2] = xa.z; x[3] = xa.w;
                x[4] = xb.x; x[5] = xb.y; x[6] = xb.z; x[7] = xb.w;
                #pragma unroll
                for (int u = 0; u < 8; ++u) {
                    int unit = ug * 8 + u;
                    float acc = A.ab1[unit];
                    #pragma unroll
                    for (int q = 0; q < 8; ++q) acc += x[q] * A.aW1[q * 32 + unit];
                    acc8[u] = acc;
                }
                if (ug == 0) {
                    *(uint4*)&XfS[r][0] = make_uint4(pk2(x[0], x[1]), pk2(x[2], x[3]),
                                                     pk2(x[4], x[5]), pk2(x[6], x[7]));
                    meanL[r] = (x[0]+x[1]+x[2]+x[3]+x[4]+x[5]+x[6]+x[7]) * 0.125f;
                }
            } else {
                int b = rg >> 4, node = rg & 15;
                float4 xa = *(const float4*)(z + b * 64 + node * 4);
                x[0] = xa.x; x[1] = xa.y; x[2] = xa.z; x[3] = xa.w;
                #pragma unroll
                for (int u = 0; u < 8; ++u) {
                    int unit = ug * 8 + u;
                    float acc = A.ab1[unit];
                    #pragma unroll
                    for (int q = 0; q < 4; ++q) acc += x[q] * A.aW1[q * 32 + unit];
                    acc8[u] = acc;
                }
                if (ug == 0) {
                    *(uint4*)&XfS[r][0] = make_uint4(pk2(x[0], x[1]), pk2(x[2], x[3]), 0u, 0u);
                    meanL[r] = (x[0]+x[1]+x[2]+x[3]) * 0.25f;
                }
            }
        } else {
            const float* zr = z + (size_t)rg * 64;
            #pragma unroll
            for (int u = 0; u < 8; ++u) acc8[u] = A.ab1[ug * 8 + u];
            float mn = 0.f;
            #pragma unroll
            for (int c = 0; c < 8; ++c) {
                float4 f0 = *(const float4*)(zr + c * 8);
                float4 f1 = *(const float4*)(zr + c * 8 + 4);
                float xs[8] = {f0.x, f0.y, f0.z, f0.w, f1.x, f1.y, f1.z, f1.w};
                if (ug == 0) {
                    *(uint4*)&XfS[r][c * 4] = make_uint4(pk2(xs[0], xs[1]), pk2(xs[2], xs[3]),
                                                         pk2(xs[4], xs[5]), pk2(xs[6], xs[7]));
                }
                #pragma unroll
                for (int q = 0; q < 8; ++q) {
                    mn += xs[q];
                    float xk = xs[q];
                    #pragma unroll
                    for (int u = 0; u < 8; ++u)
                        acc8[u] += xk * A.aW1[(c * 8 + q) * 32 + ug * 8 + u];
                }
            }
            if (ug == 0) meanL[r] = mn * (1.0f / 64.0f);
        }
        // units -> logits partials
        float part[8];
        #pragma unroll
        for (int nn = 0; nn < 8; ++nn) part[nn] = (ug == 0) ? A.ab2[nn] : 0.f;
        #pragma unroll
        for (int u = 0; u < 8; ++u) {
            int unit = ug * 8 + u;
            float a1 = silu_f(acc8[u]);
            #pragma unroll
            for (int nn = 0; nn < 8; ++nn) part[nn] += a1 * A.aW2[unit * 8 + nn];
        }
        #pragma unroll
        for (int nn = 0; nn < 8; ++nn) lgp[ug][r][nn] = part[nn];
    }
    __syncthreads();

    // combine + softmax (threads 0..127)
    if (tid < ROWS_BLK) {
        float lg[8];
        #pragma unroll
        for (int nn = 0; nn < 8; ++nn)
            lg[nn] = lgp[0][tid][nn] + lgp[1][tid][nn] + lgp[2][tid][nn] + lgp[3][tid][nn];
        float m = lg[0];
        #pragma unroll
        for (int nn = 1; nn < 8; ++nn) m = fmaxf(m, lg[nn]);
        float sum = 0.f;
        #pragma unroll
        for (int nn = 0; nn < 8; ++nn) { lg[nn] = __expf(lg[nn] - m); sum += lg[nn]; }
        float inv = fast_rcp(sum);
        float tail = 0.f;
        #pragma unroll
        for (int nn = 0; nn < 8; ++nn) {
            float a_n = lg[nn] * inv * A.scale[nn];
            tail += a_n * A.b3[nn];
            Att[tid * 9 + nn] = a_n;
        }
        Att[tid * 9 + 8] = tail + A.res[0] * meanL[tid];
    }
    __syncthreads();
    // fence: keep ALL phase-B weight loads below this point (no hoisting into phase A)
    __builtin_amdgcn_sched_barrier(0);

    // ---- Phase B weights (loaded only now; live ranges don't overlap phase A) ----
    const char* w2base = ws + w2t_off + (uint_t)(n * 8192 + g * 1024 + lo * 16);
    bf16x8 w2f0[4], w2f1[4];
    #pragma unroll
    for (int cb = 0; cb < 4; ++cb) {
        w2f0[cb] = *(const bf16x8*)(w2base + cb * 256);
        w2f1[cb] = *(const bf16x8*)(w2base + cb * 256 + 4096);
    }
    float2 bw[4];
    #pragma unroll
    for (int cb = 0; cb < 4; ++cb)
        bw[cb] = ((const float2*)(ws + bw3_off))[n * 64 + cb * 16 + lo];

    // constant x-fragment for non-data k-groups (pw/nd): g==1 k8 slot = 1.0 (bias), else 0
    union { bf16x8 v; ushort_t u[8]; } xc;
    #pragma unroll
    for (int e = 0; e < 8; ++e) xc.u[e] = 0;
    if (g == 1) xc.u[0] = f2b(1.0f);
    const bf16x8 zfr = {0, 0, 0, 0, 0, 0, 0, 0};

    if (fam != 2) {
        bf16x8 af[4];
        #pragma unroll
        for (int mt = 0; mt < 4; ++mt) {
            af[mt] = (g < 2)
                ? *(const bf16x8*)(ws + w1t_off + (uint_t)(n * 2048 + (mt * 16 + lo) * 32 + g * 16))
                : zfr;
        }
        #pragma unroll 1
        for (int t = 0; t < TILES; ++t) {
            bf16x8 xf = xc.v;
            if (g == 0) xf = *(const bf16x8*)&XfS[t * 16 + lo][0];
            const f32x4 zr4 = {0.f, 0.f, 0.f, 0.f};
            f32x4 d0 = __builtin_amdgcn_mfma_f32_16x16x32_bf16(af[0], xf, zr4, 0, 0, 0);
            f32x4 d1 = __builtin_amdgcn_mfma_f32_16x16x32_bf16(af[1], xf, zr4, 0, 0, 0);
            f32x4 d2 = __builtin_amdgcn_mfma_f32_16x16x32_bf16(af[2], xf, zr4, 0, 0, 0);
            f32x4 d3 = __builtin_amdgcn_mfma_f32_16x16x32_bf16(af[3], xf, zr4, 0, 0, 0);
            union { bf16x8 v; uint_t u[4]; } A0, A1;
            A0.u[0] = pk2(silu_f(d0[0]), silu_f(d0[1]));
            A0.u[1] = pk2(silu_f(d0[2]), silu_f(d0[3]));
            A0.u[2] = pk2(silu_f(d1[0]), silu_f(d1[1]));
            A0.u[3] = pk2(silu_f(d1[2]), silu_f(d1[3]));
            A1.u[0] = pk2(silu_f(d2[0]), silu_f(d2[1]));
            A1.u[1] = pk2(silu_f(d2[2]), silu_f(d2[3]));
            A1.u[2] = pk2(silu_f(d3[0]), silu_f(d3[1]));
            A1.u[3] = pk2(silu_f(d3[2]), silu_f(d3[3]));
            float pv0 = 0.f, pv1 = 0.f, pv2 = 0.f, pv3 = 0.f;
            #pragma unroll
            for (int cb = 0; cb < 4; ++cb) {
                f32x4 cinit = {bw[cb].x, bw[cb].x, bw[cb].x, bw[cb].x};
                f32x4 acc = __builtin_amdgcn_mfma_f32_16x16x32_bf16(A0.v, w2f0[cb], cinit, 0, 0, 0);
                acc = __builtin_amdgcn_mfma_f32_16x16x32_bf16(A1.v, w2f1[cb], acc, 0, 0, 0);
                pv0 += silu_f(acc[0]) * bw[cb].y;
                pv1 += silu_f(acc[1]) * bw[cb].y;
                pv2 += silu_f(acc[2]) * bw[cb].y;
                pv3 += silu_f(acc[3]) * bw[cb].y;
            }
            float pvv[4] = {pv0, pv1, pv2, pv3};
            #pragma unroll
            for (int r = 0; r < 4; ++r) {
                float v = pvv[r];
                v += __shfl_xor(v, 1);
                v += __shfl_xor(v, 2);
                v += __shfl_xor(v, 4);
                v += __shfl_xor(v, 8);
                if (lo == 0) {
                    int row = t * 16 + g * 4 + r;
                    Part[n][row] = Att[row * 9 + n] * v;
                }
            }
        }
    } else {
        float4 b1r[4];
        #pragma unroll
        for (int mt = 0; mt < 4; ++mt)
            b1r[mt] = *(const float4*)(ws + WS_B1D_GL + (uint_t)(n * 64 + mt * 16 + g * 4) * 4u);
        const char* w1b = ws + w1t_off + (uint_t)(n * 8192 + g * 16 + lo * 128);
        #pragma unroll 1
        for (int t = 0; t < TILES; ++t) {
            int row = t * 16 + lo;
            bf16x8 xf0 = *(const bf16x8*)&XfS[row][g * 4];
            bf16x8 xf1 = *(const bf16x8*)&XfS[row][16 + g * 4];
            const f32x4 zr4 = {0.f, 0.f, 0.f, 0.f};
            f32x4 d0 = __builtin_amdgcn_mfma_f32_16x16x32_bf16(*(const bf16x8*)(w1b + 0), xf0, zr4, 0, 0, 0);
            d0 = __builtin_amdgcn_mfma_f32_16x16x32_bf16(*(const bf16x8*)(w1b + 64), xf1, d0, 0, 0, 0);
            f32x4 d1 = __builtin_amdgcn_mfma_f32_16x16x32_bf16(*(const bf16x8*)(w1b + 2048), xf0, zr4, 0, 0, 0);
            d1 = __builtin_amdgcn_mfma_f32_16x16x32_bf16(*(const bf16x8*)(w1b + 2112), xf1, d1, 0, 0, 0);
            f32x4 d2 = __builtin_amdgcn_mfma_f32_16x16x32_bf16(*(const bf16x8*)(w1b + 4096), xf0, zr4, 0, 0, 0);
            d2 = __builtin_amdgcn_mfma_f32_16x16x32_bf16(*(const bf16x8*)(w1b + 4160), xf1, d2, 0, 0, 0);
            f32x4 d3 = __builtin_amdgcn_mfma_f32_16x16x32_bf16(*(const bf16x8*)(w1b + 6144), xf0, zr4, 0, 0, 0);
            d3 = __builtin_amdgcn_mfma_f32_16x16x32_bf16(*(const bf16x8*)(w1b + 6208), xf1, d3, 0, 0, 0);
            union { bf16x8 v; uint_t u[4]; } A0, A1;
            A0.u[0] = pk2(silu_f(d0[0] + b1r[0].x), silu_f(d0[1] + b1r[0].y));
            A0.u[1] = pk2(silu_f(d0[2] + b1r[0].z), silu_f(d0[3] + b1r[0].w));
            A0.u[2] = pk2(silu_f(d1[0] + b1r[1].x), silu_f(d1[1] + b1r[1].y));
            A0.u[3] = pk2(silu_f(d1[2] + b1r[1].z), silu_f(d1[3] + b1r[1].w));
            A1.u[0] = pk2(silu_f(d2[0] + b1r[2].x), silu_f(d2[1] + b1r[2].y));
            A1.u[1] = pk2(silu_f(d2[2] + b1r[2].z), silu_f(d2[3] + b1r[2].w));
            A1.u[2] = pk2(silu_f(d3[0] + b1r[3].x), silu_f(d3[1] + b1r[3].y));
            A1.u[3] = pk2(silu_f(d3[2] + b1r[3].z), silu_f(d3[3] + b1r[3].w));
            float pv0 = 0.f, pv1 = 0.f, pv2 = 0.f, pv3 = 0.f;
            #pragma unroll
            for (int cb = 0; cb < 4; ++cb) {
                f32x4 cinit = {bw[cb].x, bw[cb].x, bw[cb].x, bw[cb].x};
                f32x4 acc = __builtin_amdgcn_mfma_f32_16x16x32_bf16(A0.v, w2f0[cb], cinit, 0, 0, 0);
                acc = __builtin_amdgcn_mfma_f32_16x16x32_bf16(A1.v, w2f1[cb], acc, 0, 0, 0);
                pv0 += silu_f(acc[0]) * bw[cb].y;
                pv1 += silu_f(acc[1]) * bw[cb].y;
                pv2 += silu_f(acc[2]) * bw[cb].y;
                pv3 += silu_f(acc[3]) * bw[cb].y;
            }
            float pvv[4] = {pv0, pv1, pv2, pv3};
            #pragma unroll
            for (int r = 0; r < 4; ++r) {
                float v = pvv[r];
                v += __shfl_xor(v, 1);
                v += __shfl_xor(v, 2);
                v += __shfl_xor(v, 4);
                v += __shfl_xor(v, 8);
                if (lo == 0) {
                    int rw = t * 16 + g * 4 + r;
                    Part[n][rw] = Att[rw * 9 + n] * v;
                }
            }
        }
    }

    __syncthreads();

    // final cross-basis reduce + gate + store
    if (tid < ROWS_BLK) {
        float v = Att[tid * 9 + 8];   // tail
        #pragma unroll
        for (int w = 0; w < 8; ++w) v += Part[w][tid];
        v *= st_s;
        v = fminf(fmaxf(v, -1e6f), 1e6f);
        out[(size_t)st_bb * XCOLS + st_colo] = v;
    }
}

extern "C" void kernel_launch(void* const* d_in, const int* in_sizes, int n_in,
                              void* d_out, int out_size, void* d_ws, size_t ws_size,
                              hipStream_t stream) {
    const float* z = (const float*)d_in[0];
    const float* pw[12]; const float* nd[12]; const float* gl[12];
    for (int i = 0; i < 12; ++i) pw[i] = (const float*)d_in[1 + i];
    for (int i = 0; i < 12; ++i) nd[i] = (const float*)d_in[13 + i];
    for (int i = 0; i < 12; ++i) gl[i] = (const float*)d_in[25 + i];

    SArgs sel = {(const float*)d_in[37], (const float*)d_in[38], (const float*)d_in[39],
                 (const float*)d_in[40], (const float*)d_in[41], (const float*)d_in[42]};

    float* out = (float*)d_out;
    char* ws = (char*)d_ws;

    // param index order: W1,b1,W2,b2,W3,b3,scale,aW1,ab1,aW2,ab2,res
    AArgs apw = {pw[7], pw[8], pw[9], pw[10], pw[5], pw[6], pw[11]};
    AArgs anda = {nd[7], nd[8], nd[9], nd[10], nd[5], nd[6], nd[11]};
    AArgs agl = {gl[7], gl[8], gl[9], gl[10], gl[5], gl[6], gl[11]};
    PArgs ppw = {pw[0], pw[1], pw[2], pw[3], pw[4]};
    PArgs pnd = {nd[0], nd[1], nd[2], nd[3], nd[4]};
    PArgs pgl = {gl[0], gl[1], gl[2], gl[3], gl[4]};

    pre_kernel<<<PRE_SG + PRE_WP, 256, 0, stream>>>(z, sel, ppw, pnd, pgl, ws, out);

    basis_main_kernel<<<GL_BLK + PW_BLK + ND_BLK, 512, 0, stream>>>(
        ws, z, apw, anda, agl, out);
}